// Round 1
// baseline (1675.254 us; speedup 1.0000x reference)
//
#include <hip/hip_runtime.h>
#include <hip/hip_bf16.h>
#include <math.h>

// Problem constants (B, C, D, H, W = 4, 256, 32, 32, 32)
#define BATCH 4
#define CCH   256
#define NTOK  32768          // 32*32*32
#define NHEAD 8
#define DHEAD 32
#define NGRP  4
#define CPG   64             // channels per group
#define GNEPS 1e-5f

// ---- workspace layout (bytes) ----
#define OFF_GSTAT   0u            // 32 floats (sum,sumsq per (b,g))
#define OFF_GMUSIG  128u          // 32 floats (mu, rsig per (b,g))
#define OFF_KMAX    256u          // 1024 floats
#define OFF_KRSUM   4352u         // 1024 floats
#define OFF_CTX     8448u         // 4*8*32*32 floats = 131072 B
#define OFF_WCTX    139520u       // 4*256*256 floats = 1048576 B
#define OFF_QKV     1188096u      // 4*768*32768 floats = 402653184 B
#define WS_NEEDED   (OFF_QKV + 402653184ull)

// ------------------------------------------------------------------
// K1: GroupNorm partial sums.  grid (64 chunks, 16 (b,g)), 256 thr
// ------------------------------------------------------------------
__global__ __launch_bounds__(256) void gn_partial(const float* __restrict__ x,
                                                  float* __restrict__ gstat) {
  int bg = blockIdx.y;               // 0..15
  int b = bg >> 2, g = bg & 3;
  int chunk = blockIdx.x;            // 0..63  (512 tokens each)
  const float* base = x + ((size_t)b * CCH + (size_t)g * CPG) * NTOK + (size_t)chunk * 512;
  float s = 0.f, sq = 0.f;
  for (int i = threadIdx.x; i < CPG * 512; i += 256) {
    int ch = i >> 9, t = i & 511;
    float v = base[(size_t)ch * NTOK + t];
    s += v; sq += v * v;
  }
  for (int o = 32; o > 0; o >>= 1) { s += __shfl_down(s, o); sq += __shfl_down(sq, o); }
  __shared__ float rs[4], rq[4];
  int lane = threadIdx.x & 63, w = threadIdx.x >> 6;
  if (lane == 0) { rs[w] = s; rq[w] = sq; }
  __syncthreads();
  if (threadIdx.x == 0) {
    atomicAdd(&gstat[2 * bg],     rs[0] + rs[1] + rs[2] + rs[3]);
    atomicAdd(&gstat[2 * bg + 1], rq[0] + rq[1] + rq[2] + rq[3]);
  }
}

// ------------------------------------------------------------------
// K2: finalize GroupNorm stats. 1 block
// ------------------------------------------------------------------
__global__ void gn_finalize(const float* __restrict__ gstat, float* __restrict__ gmusig) {
  int i = threadIdx.x;
  if (i < 16) {
    const float cnt = (float)CPG * (float)NTOK;
    float mu  = gstat[2 * i] / cnt;
    float var = gstat[2 * i + 1] / cnt - mu * mu;
    gmusig[2 * i]     = mu;
    gmusig[2 * i + 1] = rsqrtf(var + GNEPS);
  }
}

// ------------------------------------------------------------------
// K3: qkv[b][o][n] = sum_c wqkv[o][c] * norm(x)[b][c][n]
// grid (512 n-tiles, 12 o-tiles, 4 b), 256 thr, 64x64 tile, 4x4 micro
// ------------------------------------------------------------------
__global__ __launch_bounds__(256) void qkv_gemm(const float* __restrict__ x,
                                                const float* __restrict__ gamma,
                                                const float* __restrict__ beta,
                                                const float* __restrict__ wqkv,
                                                const float* __restrict__ gmusig,
                                                float* __restrict__ qkv) {
  int b  = blockIdx.z;
  int o0 = blockIdx.y * 64;
  int n0 = blockIdx.x * 64;
  int tid = threadIdx.x;
  int tx = tid & 15, ty = tid >> 4;
  __shared__ float wt[16][68];
  __shared__ float xt[16][68];
  float acc[4][4] = {};
  const float* xb = x + (size_t)b * CCH * NTOK;

  for (int c0 = 0; c0 < CCH; c0 += 16) {
    __syncthreads();
    // stage W tile: 64 o x 16 c  -> wt[c][o]
    for (int i = tid; i < 1024; i += 256) {
      int kk = i & 15, oo = i >> 4;
      wt[kk][oo] = wqkv[(size_t)(o0 + oo) * CCH + c0 + kk];
    }
    // stage normalized x tile: 16 c x 64 n
    for (int i = tid; i < 1024; i += 256) {
      int kk = i >> 6, nn = i & 63;
      int c = c0 + kk;
      int g = c >> 6;
      float mu = gmusig[2 * (b * 4 + g)];
      float rs = gmusig[2 * (b * 4 + g) + 1];
      float v = xb[(size_t)c * NTOK + n0 + nn];
      xt[kk][nn] = (v - mu) * rs * gamma[c] + beta[c];
    }
    __syncthreads();
#pragma unroll
    for (int kk = 0; kk < 16; ++kk) {
      float4 a  = *reinterpret_cast<const float4*>(&wt[kk][ty * 4]);
      float4 bb = *reinterpret_cast<const float4*>(&xt[kk][tx * 4]);
      float av[4] = {a.x, a.y, a.z, a.w};
      float bv[4] = {bb.x, bb.y, bb.z, bb.w};
#pragma unroll
      for (int i = 0; i < 4; ++i)
#pragma unroll
        for (int j = 0; j < 4; ++j) acc[i][j] += av[i] * bv[j];
    }
  }
  // write out
#pragma unroll
  for (int i = 0; i < 4; ++i) {
    int o = o0 + ty * 4 + i;
    float4 r = make_float4(acc[i][0], acc[i][1], acc[i][2], acc[i][3]);
    *reinterpret_cast<float4*>(&qkv[((size_t)b * 768 + o) * NTOK + n0 + tx * 4]) = r;
  }
}

// ------------------------------------------------------------------
// K4: per-row max and 1/sum(exp) for k.  grid 1024 rows (b*256+hd)
// ------------------------------------------------------------------
__global__ __launch_bounds__(256) void k_maxsum(const float* __restrict__ qkv,
                                                float* __restrict__ kmax,
                                                float* __restrict__ krsum) {
  int r = blockIdx.x;
  int b = r >> 8, hd = r & 255;
  const float* row = qkv + ((size_t)b * 768 + 256 + hd) * NTOK;
  float m = -1e30f;
  for (int i = threadIdx.x; i < NTOK; i += 256) m = fmaxf(m, row[i]);
  for (int o = 32; o > 0; o >>= 1) m = fmaxf(m, __shfl_down(m, o));
  __shared__ float sm[4], ss[4];
  int lane = threadIdx.x & 63, w = threadIdx.x >> 6;
  if (lane == 0) sm[w] = m;
  __syncthreads();
  float M = fmaxf(fmaxf(sm[0], sm[1]), fmaxf(sm[2], sm[3]));
  float s = 0.f;
  for (int i = threadIdx.x; i < NTOK; i += 256) s += __expf(row[i] - M);
  for (int o = 32; o > 0; o >>= 1) s += __shfl_down(s, o);
  if (lane == 0) ss[w] = s;
  __syncthreads();
  if (threadIdx.x == 0) {
    kmax[r]  = M;
    krsum[r] = 1.f / (ss[0] + ss[1] + ss[2] + ss[3]);
  }
}

// ------------------------------------------------------------------
// K5: ctx[b][h][d][e] += sum_n softmax(k)[d][n] * v[e][n]
// grid (32 n-chunks of 1024, 32 (b,h)), 256 thr, 2x2 micro
// ------------------------------------------------------------------
__global__ __launch_bounds__(256) void context_partial(const float* __restrict__ qkv,
                                                       const float* __restrict__ kmax,
                                                       const float* __restrict__ krsum,
                                                       float* __restrict__ ctx) {
  int bh = blockIdx.y;               // 0..31
  int b = bh >> 3, h = bh & 7;
  int n0 = blockIdx.x * 1024;
  const float* kb = qkv + ((size_t)b * 768 + 256 + h * 32) * NTOK;
  const float* vb = qkv + ((size_t)b * 768 + 512 + h * 32) * NTOK;
  __shared__ float kt[32][257];
  __shared__ float vt[32][257];
  int tid = threadIdx.x;
  int d2 = (tid >> 4) * 2;
  int e2 = (tid & 15) * 2;
  int rbase = b * 256 + h * 32;
  float acc[2][2] = {};
  for (int sub = 0; sub < 4; ++sub) {
    int nb = n0 + sub * 256;
    __syncthreads();
    for (int i = tid; i < 32 * 256; i += 256) {
      int d = i >> 8, t = i & 255;
      float kv = kb[(size_t)d * NTOK + nb + t];
      kt[d][t] = __expf(kv - kmax[rbase + d]) * krsum[rbase + d];
      vt[d][t] = vb[(size_t)d * NTOK + nb + t];
    }
    __syncthreads();
#pragma unroll 8
    for (int t = 0; t < 256; ++t) {
      float k0 = kt[d2][t], k1 = kt[d2 + 1][t];
      float v0 = vt[e2][t], v1 = vt[e2 + 1][t];
      acc[0][0] += k0 * v0; acc[0][1] += k0 * v1;
      acc[1][0] += k1 * v0; acc[1][1] += k1 * v1;
    }
  }
  float* cb = ctx + (size_t)bh * 1024;
  atomicAdd(&cb[(d2)     * 32 + e2],     acc[0][0]);
  atomicAdd(&cb[(d2)     * 32 + e2 + 1], acc[0][1]);
  atomicAdd(&cb[(d2 + 1) * 32 + e2],     acc[1][0]);
  atomicAdd(&cb[(d2 + 1) * 32 + e2 + 1], acc[1][1]);
}

// ------------------------------------------------------------------
// K5b: wctx[b][o][h*32+d] = sum_e wout[o][h*32+e] * ctx[b][h][d][e]
// grid (256 o, 4 b), 256 thr (one per c' = h*32+d)
// ------------------------------------------------------------------
__global__ __launch_bounds__(256) void make_wctx(const float* __restrict__ wout,
                                                 const float* __restrict__ ctx,
                                                 float* __restrict__ wctx) {
  int o = blockIdx.x, b = blockIdx.y;
  int tid = threadIdx.x;
  int h = tid >> 5, d = tid & 31;
  const float* cb = ctx + ((size_t)(b * 8 + h)) * 1024 + d * 32;
  const float* wr = wout + (size_t)o * 256 + h * 32;
  float s = 0.f;
#pragma unroll
  for (int e = 0; e < 32; ++e) s += wr[e] * cb[e];
  wctx[((size_t)b * 256 + o) * 256 + tid] = s;
}

// ------------------------------------------------------------------
// K6: out[b][o][n] = sum_c wctx[b][o][c] * softmax_d(q)[c][n] + b_out[o] + x[b][o][n]
// grid (512 n-tiles, 4 o-tiles, 4 b), 256 thr, 64x64 tile, 4x4 micro
// ------------------------------------------------------------------
__global__ __launch_bounds__(256) void out_gemm(const float* __restrict__ qkv,
                                                const float* __restrict__ wctx,
                                                const float* __restrict__ bout,
                                                const float* __restrict__ x,
                                                float* __restrict__ out) {
  int b  = blockIdx.z;
  int o0 = blockIdx.y * 64;
  int n0 = blockIdx.x * 64;
  int tid = threadIdx.x;
  __shared__ float qt[256][68];
  __shared__ float wt[16][68];
  const float* qb = qkv + (size_t)b * 768 * NTOK;

  // load q tile (raw)
  for (int i = tid; i < 256 * 64; i += 256) {
    int cc = i >> 6, nn = i & 63;
    qt[cc][nn] = qb[(size_t)cc * NTOK + n0 + nn];
  }
  __syncthreads();
  // softmax over d (32 rows per head), per (head, token)
  for (int task = tid; task < 512; task += 256) {
    int hh = task >> 6, nn = task & 63;
    float m = -1e30f;
#pragma unroll
    for (int d = 0; d < 32; ++d) m = fmaxf(m, qt[hh * 32 + d][nn]);
    float s = 0.f;
#pragma unroll
    for (int d = 0; d < 32; ++d) s += __expf(qt[hh * 32 + d][nn] - m);
    float r = 1.f / s;
#pragma unroll
    for (int d = 0; d < 32; ++d) qt[hh * 32 + d][nn] = __expf(qt[hh * 32 + d][nn] - m) * r;
  }

  int tx = tid & 15, ty = tid >> 4;
  float acc[4][4] = {};
  const float* wb = wctx + ((size_t)b * 256 + o0) * 256;
  for (int c0 = 0; c0 < 256; c0 += 16) {
    __syncthreads();
    for (int i = tid; i < 1024; i += 256) {
      int kk = i & 15, oo = i >> 4;
      wt[kk][oo] = wb[(size_t)oo * 256 + c0 + kk];
    }
    __syncthreads();
#pragma unroll
    for (int kk = 0; kk < 16; ++kk) {
      float4 a  = *reinterpret_cast<const float4*>(&wt[kk][ty * 4]);
      float4 bb = *reinterpret_cast<const float4*>(&qt[c0 + kk][tx * 4]);
      float av[4] = {a.x, a.y, a.z, a.w};
      float bv[4] = {bb.x, bb.y, bb.z, bb.w};
#pragma unroll
      for (int i = 0; i < 4; ++i)
#pragma unroll
        for (int j = 0; j < 4; ++j) acc[i][j] += av[i] * bv[j];
    }
  }
  // epilogue: + bias + residual, write
  const float* xb = x + (size_t)b * CCH * NTOK;
#pragma unroll
  for (int i = 0; i < 4; ++i) {
    int o = o0 + ty * 4 + i;
    float bo = bout[o];
    float4 xv = *reinterpret_cast<const float4*>(&xb[(size_t)o * NTOK + n0 + tx * 4]);
    float4 r = make_float4(acc[i][0] + bo + xv.x, acc[i][1] + bo + xv.y,
                           acc[i][2] + bo + xv.z, acc[i][3] + bo + xv.w);
    *reinterpret_cast<float4*>(&out[((size_t)b * CCH + o) * NTOK + n0 + tx * 4]) = r;
  }
}

// ------------------------------------------------------------------
extern "C" void kernel_launch(void* const* d_in, const int* in_sizes, int n_in,
                              void* d_out, int out_size, void* d_ws, size_t ws_size,
                              hipStream_t stream) {
  const float* x     = (const float*)d_in[0];
  const float* gamma = (const float*)d_in[1];
  const float* beta  = (const float*)d_in[2];
  const float* wqkv  = (const float*)d_in[3];
  const float* wout  = (const float*)d_in[4];
  const float* bout  = (const float*)d_in[5];
  float* out = (float*)d_out;

  if (ws_size < WS_NEEDED) return;  // scratch too small: bail cleanly

  char* ws = (char*)d_ws;
  float* gstat  = (float*)(ws + OFF_GSTAT);
  float* gmusig = (float*)(ws + OFF_GMUSIG);
  float* kmax   = (float*)(ws + OFF_KMAX);
  float* krsum  = (float*)(ws + OFF_KRSUM);
  float* ctx    = (float*)(ws + OFF_CTX);
  float* wctx   = (float*)(ws + OFF_WCTX);
  float* qkv    = (float*)(ws + OFF_QKV);

  // zero accumulators (gstat + ctx; everything in between is overwritten)
  hipMemsetAsync(ws, 0, OFF_CTX + 131072u, stream);

  gn_partial  <<<dim3(64, 16), 256, 0, stream>>>(x, gstat);
  gn_finalize <<<1, 64, 0, stream>>>(gstat, gmusig);
  qkv_gemm    <<<dim3(512, 12, 4), 256, 0, stream>>>(x, gamma, beta, wqkv, gmusig, qkv);
  k_maxsum    <<<1024, 256, 0, stream>>>(qkv, kmax, krsum);
  context_partial<<<dim3(32, 32), 256, 0, stream>>>(qkv, kmax, krsum, ctx);
  make_wctx   <<<dim3(256, 4), 256, 0, stream>>>(wout, ctx, wctx);
  out_gemm    <<<dim3(512, 4, 4), 256, 0, stream>>>(qkv, wctx, bout, x, out);
}

// Round 2
// 525.087 us; speedup vs baseline: 3.1904x; 3.1904x over previous
//
#include <hip/hip_runtime.h>
#include <hip/hip_bf16.h>
#include <math.h>

#define BATCH 4
#define CCH   256
#define NTOK  32768
#define NHEAD 8
#define DHEAD 32
#define CPG   64
#define GNEPS 1e-5f

typedef __attribute__((ext_vector_type(4))) float f32x4;
typedef __attribute__((ext_vector_type(8))) short s16x8;
typedef __attribute__((ext_vector_type(4))) unsigned short u16x4;

__device__ __forceinline__ unsigned short f2b(float f) {
  unsigned int u = __float_as_uint(f);
  unsigned int r = (u + 0x7FFFu + ((u >> 16) & 1u)) >> 16;
  return (unsigned short)r;
}
__device__ __forceinline__ float b2f(unsigned short s) {
  return __uint_as_float(((unsigned int)s) << 16);
}

// ---- workspace layout (bytes) ----
#define OFF_GSTAT   0u
#define OFF_GMUSIG  128u
#define OFF_KMAX    256u
#define OFF_KRSUM   4352u
#define OFF_CTX     8448u          // 4*8*32*32 f32 = 131072
#define OFF_WCTXB   139520u        // 4*256*256 bf16 = 524288
#define OFF_WQKVB   663808u        // 768*256 bf16 = 393216
#define OFF_QKVB    1057024u       // 4*768*32768 bf16 = 201326592
#define WS_NEEDED   (OFF_QKVB + 201326592ull)

// ------------------------------------------------------------------
// K1: GroupNorm partial sums
// ------------------------------------------------------------------
__global__ __launch_bounds__(256) void gn_partial(const float* __restrict__ x,
                                                  float* __restrict__ gstat) {
  int bg = blockIdx.y;
  int b = bg >> 2, g = bg & 3;
  int chunk = blockIdx.x;
  const float* base = x + ((size_t)b * CCH + (size_t)g * CPG) * NTOK + (size_t)chunk * 512;
  float s = 0.f, sq = 0.f;
  for (int i = threadIdx.x; i < CPG * 512; i += 256) {
    int ch = i >> 9, t = i & 511;
    float v = base[(size_t)ch * NTOK + t];
    s += v; sq += v * v;
  }
  for (int o = 32; o > 0; o >>= 1) { s += __shfl_down(s, o); sq += __shfl_down(sq, o); }
  __shared__ float rs[4], rq[4];
  int lane = threadIdx.x & 63, w = threadIdx.x >> 6;
  if (lane == 0) { rs[w] = s; rq[w] = sq; }
  __syncthreads();
  if (threadIdx.x == 0) {
    atomicAdd(&gstat[2 * bg],     rs[0] + rs[1] + rs[2] + rs[3]);
    atomicAdd(&gstat[2 * bg + 1], rq[0] + rq[1] + rq[2] + rq[3]);
  }
}

__global__ void gn_finalize(const float* __restrict__ gstat, float* __restrict__ gmusig) {
  int i = threadIdx.x;
  if (i < 16) {
    const float cnt = (float)CPG * (float)NTOK;
    float mu  = gstat[2 * i] / cnt;
    float var = gstat[2 * i + 1] / cnt - mu * mu;
    gmusig[2 * i]     = mu;
    gmusig[2 * i + 1] = rsqrtf(var + GNEPS);
  }
}

// ------------------------------------------------------------------
// K2b: convert w_qkv f32 -> bf16   (192 blocks x 256 thr, 4 elems each)
// ------------------------------------------------------------------
__global__ __launch_bounds__(256) void cvt_w(const float* __restrict__ w,
                                             unsigned short* __restrict__ wb) {
  int i = blockIdx.x * 256 + threadIdx.x;
  f32x4 v = *reinterpret_cast<const f32x4*>(&w[(size_t)i * 4]);
  u16x4 o = { f2b(v.x), f2b(v.y), f2b(v.z), f2b(v.w) };
  *reinterpret_cast<u16x4*>(&wb[(size_t)i * 4]) = o;
}

// ------------------------------------------------------------------
// K3: qkv bf16 = wqkv_b (bf16) @ norm(x) (bf16), MFMA 16x16x32
// grid (512 n-tiles, 4 b), 256 thr = 4 waves; wave: 64o x 64n, 3 o-passes
// ------------------------------------------------------------------
__global__ __launch_bounds__(256) void qkv_gemm(const float* __restrict__ x,
                                                const float* __restrict__ gamma,
                                                const float* __restrict__ beta,
                                                const unsigned short* __restrict__ wqkvb,
                                                const float* __restrict__ gmusig,
                                                unsigned short* __restrict__ qkvb) {
  __shared__ unsigned short s1[128 * 72];   // row-major bf16 half-tile [c][n], pad 72
  __shared__ unsigned short xt[64 * 256];   // [n][c] XOR-swizzled (16B blocks ^ (n&7))
  int b  = blockIdx.y;
  int n0 = blockIdx.x * 64;
  int tid = threadIdx.x;
  int w = tid >> 6, l = tid & 63;
  const float* xb = x + (size_t)b * CCH * NTOK;

  for (int half = 0; half < 2; ++half) {
    int cbase = half * 128;
    // stage1: coalesced f32 reads, normalize, bf16, row-major LDS
    for (int u = tid; u < 2048; u += 256) {
      int cl = u >> 4, q = u & 15;
      int c = cbase + cl;
      int g = c >> 6;
      float mu = gmusig[2 * (b * 4 + g)], rs = gmusig[2 * (b * 4 + g) + 1];
      float ga = gamma[c] * rs;
      float be = beta[c] - mu * ga;
      f32x4 v = *reinterpret_cast<const f32x4*>(&xb[(size_t)c * NTOK + n0 + q * 4]);
      u16x4 o = { f2b(v.x * ga + be), f2b(v.y * ga + be),
                  f2b(v.z * ga + be), f2b(v.w * ga + be) };
      *reinterpret_cast<u16x4*>(&s1[cl * 72 + q * 4]) = o;
    }
    __syncthreads();
    // transpose: column reads (2-way, free) -> packed b128 swizzled writes
    for (int u = tid; u < 1024; u += 256) {
      int n = u & 63, kb = u >> 6;        // kb 0..15 within half
      int kbl = half * 16 + kb;           // absolute 8-elem block of c
      int crow = kb * 8;
      s16x8 pk;
#pragma unroll
      for (int i = 0; i < 8; ++i) pk[i] = (short)s1[(crow + i) * 72 + n];
      int phys = kbl ^ (n & 7);
      *reinterpret_cast<s16x8*>(&xt[n * 256 + phys * 8]) = pk;
    }
    __syncthreads();
  }

  // MFMA: 3 passes over o (256 each), wave covers 64 o
  for (int p = 0; p < 3; ++p) {
    f32x4 acc[4][4];
#pragma unroll
    for (int s = 0; s < 4; ++s)
#pragma unroll
      for (int nt = 0; nt < 4; ++nt) acc[s][nt] = (f32x4){0.f, 0.f, 0.f, 0.f};

    for (int t = 0; t < 8; ++t) {
      s16x8 af[4], bf[4];
#pragma unroll
      for (int s = 0; s < 4; ++s) {
        int o = p * 256 + w * 64 + s * 16 + (l & 15);
        af[s] = *reinterpret_cast<const s16x8*>(&wqkvb[(size_t)o * 256 + t * 32 + (l >> 4) * 8]);
      }
#pragma unroll
      for (int nt = 0; nt < 4; ++nt) {
        int r = nt * 16 + (l & 15);
        int phys = (t * 4 + (l >> 4)) ^ (r & 7);
        bf[nt] = *reinterpret_cast<const s16x8*>(&xt[r * 256 + phys * 8]);
      }
#pragma unroll
      for (int s = 0; s < 4; ++s)
#pragma unroll
        for (int nt = 0; nt < 4; ++nt)
          acc[s][nt] = __builtin_amdgcn_mfma_f32_16x16x32_bf16(af[s], bf[nt], acc[s][nt], 0, 0, 0);
    }
#pragma unroll
    for (int s = 0; s < 4; ++s)
#pragma unroll
      for (int nt = 0; nt < 4; ++nt)
#pragma unroll
        for (int i = 0; i < 4; ++i) {
          int o = p * 256 + w * 64 + s * 16 + (l >> 4) * 4 + i;
          int n = n0 + nt * 16 + (l & 15);
          qkvb[(size_t)(b * 768 + o) * NTOK + n] = f2b(acc[s][nt][i]);
        }
  }
}

// ------------------------------------------------------------------
// K4: per-row max and 1/sum(exp) for k (bf16 input)
// ------------------------------------------------------------------
__global__ __launch_bounds__(256) void k_maxsum(const unsigned short* __restrict__ qkvb,
                                                float* __restrict__ kmax,
                                                float* __restrict__ krsum) {
  int r = blockIdx.x;
  int b = r >> 8, hd = r & 255;
  const unsigned short* row = qkvb + ((size_t)(b * 768) + 256 + hd) * NTOK;
  int tid = threadIdx.x;
  float m = -1e30f;
  for (int i = tid; i < 4096; i += 256) {
    s16x8 v = *reinterpret_cast<const s16x8*>(&row[i * 8]);
#pragma unroll
    for (int j = 0; j < 8; ++j) m = fmaxf(m, b2f((unsigned short)v[j]));
  }
  for (int o = 32; o > 0; o >>= 1) m = fmaxf(m, __shfl_down(m, o));
  __shared__ float sm[4], ss[4];
  int lane = tid & 63, w = tid >> 6;
  if (lane == 0) sm[w] = m;
  __syncthreads();
  float M = fmaxf(fmaxf(sm[0], sm[1]), fmaxf(sm[2], sm[3]));
  float s = 0.f;
  for (int i = tid; i < 4096; i += 256) {
    s16x8 v = *reinterpret_cast<const s16x8*>(&row[i * 8]);
#pragma unroll
    for (int j = 0; j < 8; ++j) s += __expf(b2f((unsigned short)v[j]) - M);
  }
  for (int o = 32; o > 0; o >>= 1) s += __shfl_down(s, o);
  if (lane == 0) ss[w] = s;
  __syncthreads();
  if (tid == 0) {
    kmax[r]  = M;
    krsum[r] = 1.f / (ss[0] + ss[1] + ss[2] + ss[3]);
  }
}

// ------------------------------------------------------------------
// K5: ctx[b][h][d][e] += sum_n softmax(k)[d][n] * v[e][n]  (bf16 in)
// ------------------------------------------------------------------
__global__ __launch_bounds__(256) void context_partial(const unsigned short* __restrict__ qkvb,
                                                       const float* __restrict__ kmax,
                                                       const float* __restrict__ krsum,
                                                       float* __restrict__ ctx) {
  int bh = blockIdx.y;
  int b = bh >> 3, h = bh & 7;
  int n0 = blockIdx.x * 1024;
  const unsigned short* kb = qkvb + ((size_t)b * 768 + 256 + h * 32) * NTOK;
  const unsigned short* vb = qkvb + ((size_t)b * 768 + 512 + h * 32) * NTOK;
  __shared__ float kt[32][260];
  __shared__ float vt[32][260];
  int tid = threadIdx.x;
  int d2 = (tid >> 4) * 2;
  int e2 = (tid & 15) * 2;
  int rbase = b * 256 + h * 32;
  float acc[2][2] = {};
  for (int sub = 0; sub < 4; ++sub) {
    int nb = n0 + sub * 256;
    __syncthreads();
    // stage: 32 d x 32 octets per matrix; coalesced 16B loads, float4 LDS writes
    for (int u = tid; u < 1024; u += 256) {
      int d = u >> 5, oc = u & 31;
      float km = kmax[rbase + d], kr = krsum[rbase + d];
      s16x8 kv = *reinterpret_cast<const s16x8*>(&kb[(size_t)d * NTOK + nb + oc * 8]);
      s16x8 vv = *reinterpret_cast<const s16x8*>(&vb[(size_t)d * NTOK + nb + oc * 8]);
      f32x4 k0 = { __expf(b2f((unsigned short)kv[0]) - km) * kr,
                   __expf(b2f((unsigned short)kv[1]) - km) * kr,
                   __expf(b2f((unsigned short)kv[2]) - km) * kr,
                   __expf(b2f((unsigned short)kv[3]) - km) * kr };
      f32x4 k1 = { __expf(b2f((unsigned short)kv[4]) - km) * kr,
                   __expf(b2f((unsigned short)kv[5]) - km) * kr,
                   __expf(b2f((unsigned short)kv[6]) - km) * kr,
                   __expf(b2f((unsigned short)kv[7]) - km) * kr };
      f32x4 v0 = { b2f((unsigned short)vv[0]), b2f((unsigned short)vv[1]),
                   b2f((unsigned short)vv[2]), b2f((unsigned short)vv[3]) };
      f32x4 v1 = { b2f((unsigned short)vv[4]), b2f((unsigned short)vv[5]),
                   b2f((unsigned short)vv[6]), b2f((unsigned short)vv[7]) };
      *reinterpret_cast<f32x4*>(&kt[d][oc * 8])     = k0;
      *reinterpret_cast<f32x4*>(&kt[d][oc * 8 + 4]) = k1;
      *reinterpret_cast<f32x4*>(&vt[d][oc * 8])     = v0;
      *reinterpret_cast<f32x4*>(&vt[d][oc * 8 + 4]) = v1;
    }
    __syncthreads();
#pragma unroll 8
    for (int t = 0; t < 256; ++t) {
      float k0 = kt[d2][t], k1 = kt[d2 + 1][t];
      float v0 = vt[e2][t], v1 = vt[e2 + 1][t];
      acc[0][0] += k0 * v0; acc[0][1] += k0 * v1;
      acc[1][0] += k1 * v0; acc[1][1] += k1 * v1;
    }
  }
  float* cb = ctx + (size_t)bh * 1024;
  atomicAdd(&cb[(d2)     * 32 + e2],     acc[0][0]);
  atomicAdd(&cb[(d2)     * 32 + e2 + 1], acc[0][1]);
  atomicAdd(&cb[(d2 + 1) * 32 + e2],     acc[1][0]);
  atomicAdd(&cb[(d2 + 1) * 32 + e2 + 1], acc[1][1]);
}

// ------------------------------------------------------------------
// K5b: wctx_b[b][o][h*32+d] = bf16( sum_e wout[o][h*32+e] * ctx[b][h][d][e] )
// ------------------------------------------------------------------
__global__ __launch_bounds__(256) void make_wctx(const float* __restrict__ wout,
                                                 const float* __restrict__ ctx,
                                                 unsigned short* __restrict__ wctxb) {
  int o = blockIdx.x, b = blockIdx.y;
  int tid = threadIdx.x;
  int h = tid >> 5, d = tid & 31;
  const float* cb = ctx + ((size_t)(b * 8 + h)) * 1024 + d * 32;
  const float* wr = wout + (size_t)o * 256 + h * 32;
  float s = 0.f;
#pragma unroll
  for (int e = 0; e < 32; ++e) s += wr[e] * cb[e];
  wctxb[((size_t)b * 256 + o) * 256 + tid] = f2b(s);
}

// ------------------------------------------------------------------
// K6: out = wctx_b @ softmax_d(q) + bias + x   (MFMA, q softmax fused)
// grid (512 n-tiles, 4 b), 256 thr; wave: 64o x 64n, single o-pass
// ------------------------------------------------------------------
__global__ __launch_bounds__(256) void out_gemm(const unsigned short* __restrict__ qkvb,
                                                const unsigned short* __restrict__ wctxb,
                                                const float* __restrict__ bout,
                                                const float* __restrict__ x,
                                                float* __restrict__ out) {
  __shared__ unsigned short s1[128 * 72];
  __shared__ unsigned short xt[64 * 256];
  int b  = blockIdx.y;
  int n0 = blockIdx.x * 64;
  int tid = threadIdx.x;
  int w = tid >> 6, l = tid & 63;
  const unsigned short* qb = qkvb + (size_t)b * 768 * NTOK;

  for (int half = 0; half < 2; ++half) {
    int cbase = half * 128;
    for (int u = tid; u < 2048; u += 256) {
      int cl = u >> 4, q = u & 15;
      u16x4 v = *reinterpret_cast<const u16x4*>(&qb[(size_t)(cbase + cl) * NTOK + n0 + q * 4]);
      *reinterpret_cast<u16x4*>(&s1[cl * 72 + q * 4]) = v;
    }
    __syncthreads();
    // softmax over d (32) per (head, token); 4 heads per half, 1 task/thread
    {
      int hl = tid >> 6;        // 0..3
      int n  = tid & 63;
      float vals[32];
#pragma unroll
      for (int d = 0; d < 32; ++d) vals[d] = b2f(s1[(hl * 32 + d) * 72 + n]);
      float m = vals[0];
#pragma unroll
      for (int d = 1; d < 32; ++d) m = fmaxf(m, vals[d]);
      float ssum = 0.f;
#pragma unroll
      for (int d = 0; d < 32; ++d) { vals[d] = __expf(vals[d] - m); ssum += vals[d]; }
      float rr = 1.f / ssum;
#pragma unroll
      for (int j = 0; j < 4; ++j) {
        int kbl = half * 16 + hl * 4 + j;
        s16x8 pk;
#pragma unroll
        for (int i = 0; i < 8; ++i) pk[i] = (short)f2b(vals[j * 8 + i] * rr);
        int phys = kbl ^ (n & 7);
        *reinterpret_cast<s16x8*>(&xt[n * 256 + phys * 8]) = pk;
      }
    }
    __syncthreads();
  }

  f32x4 acc[4][4];
#pragma unroll
  for (int s = 0; s < 4; ++s)
#pragma unroll
    for (int nt = 0; nt < 4; ++nt) acc[s][nt] = (f32x4){0.f, 0.f, 0.f, 0.f};

  const unsigned short* wb = wctxb + (size_t)b * 256 * 256;
  for (int t = 0; t < 8; ++t) {
    s16x8 af[4], bf[4];
#pragma unroll
    for (int s = 0; s < 4; ++s) {
      int o = w * 64 + s * 16 + (l & 15);
      af[s] = *reinterpret_cast<const s16x8*>(&wb[(size_t)o * 256 + t * 32 + (l >> 4) * 8]);
    }
#pragma unroll
    for (int nt = 0; nt < 4; ++nt) {
      int r = nt * 16 + (l & 15);
      int phys = (t * 4 + (l >> 4)) ^ (r & 7);
      bf[nt] = *reinterpret_cast<const s16x8*>(&xt[r * 256 + phys * 8]);
    }
#pragma unroll
    for (int s = 0; s < 4; ++s)
#pragma unroll
      for (int nt = 0; nt < 4; ++nt)
        acc[s][nt] = __builtin_amdgcn_mfma_f32_16x16x32_bf16(af[s], bf[nt], acc[s][nt], 0, 0, 0);
  }

  const float* xb = x + (size_t)b * CCH * NTOK;
#pragma unroll
  for (int s = 0; s < 4; ++s)
#pragma unroll
    for (int i = 0; i < 4; ++i) {
      int o = w * 64 + s * 16 + (l >> 4) * 4 + i;
      float bo = bout[o];
#pragma unroll
      for (int nt = 0; nt < 4; ++nt) {
        int n = n0 + nt * 16 + (l & 15);
        float xv = xb[(size_t)o * NTOK + n];
        out[((size_t)b * CCH + o) * NTOK + n] = acc[s][nt][i] + bo + xv;
      }
    }
}

// ------------------------------------------------------------------
extern "C" void kernel_launch(void* const* d_in, const int* in_sizes, int n_in,
                              void* d_out, int out_size, void* d_ws, size_t ws_size,
                              hipStream_t stream) {
  const float* x     = (const float*)d_in[0];
  const float* gamma = (const float*)d_in[1];
  const float* beta  = (const float*)d_in[2];
  const float* wqkv  = (const float*)d_in[3];
  const float* wout  = (const float*)d_in[4];
  const float* bout  = (const float*)d_in[5];
  float* out = (float*)d_out;

  if (ws_size < WS_NEEDED) return;

  char* ws = (char*)d_ws;
  float* gstat  = (float*)(ws + OFF_GSTAT);
  float* gmusig = (float*)(ws + OFF_GMUSIG);
  float* kmax   = (float*)(ws + OFF_KMAX);
  float* krsum  = (float*)(ws + OFF_KRSUM);
  float* ctx    = (float*)(ws + OFF_CTX);
  unsigned short* wctxb = (unsigned short*)(ws + OFF_WCTXB);
  unsigned short* wqkvb = (unsigned short*)(ws + OFF_WQKVB);
  unsigned short* qkvb  = (unsigned short*)(ws + OFF_QKVB);

  hipMemsetAsync(ws, 0, OFF_CTX + 131072u, stream);

  gn_partial  <<<dim3(64, 16), 256, 0, stream>>>(x, gstat);
  gn_finalize <<<1, 64, 0, stream>>>(gstat, gmusig);
  cvt_w       <<<192, 256, 0, stream>>>(wqkv, wqkvb);
  qkv_gemm    <<<dim3(512, 4), 256, 0, stream>>>(x, gamma, beta, wqkvb, gmusig, qkvb);
  k_maxsum    <<<1024, 256, 0, stream>>>(qkvb, kmax, krsum);
  context_partial<<<dim3(32, 32), 256, 0, stream>>>(qkvb, kmax, krsum, ctx);
  make_wctx   <<<dim3(256, 4), 256, 0, stream>>>(wout, ctx, wctxb);
  out_gemm    <<<dim3(512, 4), 256, 0, stream>>>(qkvb, wctxb, bout, x, out);
}

// Round 3
// 426.573 us; speedup vs baseline: 3.9272x; 1.2309x over previous
//
#include <hip/hip_runtime.h>
#include <hip/hip_bf16.h>
#include <math.h>

#define NTOK  32768
#define GNEPS 1e-5f

typedef __attribute__((ext_vector_type(4))) float f32x4;
typedef __attribute__((ext_vector_type(8))) short s16x8;
typedef __attribute__((ext_vector_type(4))) unsigned short u16x4;

__device__ __forceinline__ unsigned short f2b(float f) {
  unsigned int u = __float_as_uint(f);
  unsigned int r = (u + 0x7FFFu + ((u >> 16) & 1u)) >> 16;
  return (unsigned short)r;
}
__device__ __forceinline__ float b2f(unsigned short s) {
  return __uint_as_float(((unsigned int)s) << 16);
}

// global->LDS direct staging, 16B per lane; LDS base must be wave-uniform.
__device__ __forceinline__ void stage16(const unsigned short* g, unsigned short* ldsChunkBase, int lane) {
#if __has_builtin(__builtin_amdgcn_global_load_lds)
  __builtin_amdgcn_global_load_lds((const __attribute__((address_space(1))) void*)g,
                                   (__attribute__((address_space(3))) void*)ldsChunkBase, 16, 0, 0);
#else
  *(s16x8*)((char*)ldsChunkBase + lane * 16) = *(const s16x8*)g;
#endif
}

// ---- workspace layout (bytes) ----
#define OFF_GSTAT   0u
#define OFF_GMUSIG  128u
#define OFF_KMAX    256u
#define OFF_KRSUM   4352u
#define OFF_CTX     8448u            // 4*8*32*32 f32 = 131072
#define OFF_WCTXB   139520u          // 4*256*256 bf16 = 524288
#define OFF_WQKVB   663808u          // 768*256 bf16 = 393216
#define OFF_XNT     1057024u         // 4*32768*256 bf16 = 67108864
#define OFF_QT      68165888u        // 4*32768*256 bf16 = 67108864
#define OFF_KVB     135274752u       // 4*512*32768 bf16 = 134217728
#define WS_NEEDED   (OFF_KVB + 134217728ull)

// ------------------------------------------------------------------
// K1: GroupNorm partial sums
// ------------------------------------------------------------------
__global__ __launch_bounds__(256) void gn_partial(const float* __restrict__ x,
                                                  float* __restrict__ gstat) {
  int bg = blockIdx.y;
  int b = bg >> 2, g = bg & 3;
  int chunk = blockIdx.x;
  const float* base = x + ((size_t)b * 256 + (size_t)g * 64) * NTOK + (size_t)chunk * 512;
  float s = 0.f, sq = 0.f;
  for (int i = threadIdx.x; i < 64 * 512; i += 256) {
    int ch = i >> 9, t = i & 511;
    float v = base[(size_t)ch * NTOK + t];
    s += v; sq += v * v;
  }
  for (int o = 32; o > 0; o >>= 1) { s += __shfl_down(s, o); sq += __shfl_down(sq, o); }
  __shared__ float rs[4], rq[4];
  int lane = threadIdx.x & 63, w = threadIdx.x >> 6;
  if (lane == 0) { rs[w] = s; rq[w] = sq; }
  __syncthreads();
  if (threadIdx.x == 0) {
    atomicAdd(&gstat[2 * bg],     rs[0] + rs[1] + rs[2] + rs[3]);
    atomicAdd(&gstat[2 * bg + 1], rq[0] + rq[1] + rq[2] + rq[3]);
  }
}

__global__ void gn_finalize(const float* __restrict__ gstat, float* __restrict__ gmusig) {
  int i = threadIdx.x;
  if (i < 16) {
    const float cnt = 64.f * (float)NTOK;
    float mu  = gstat[2 * i] / cnt;
    float var = gstat[2 * i + 1] / cnt - mu * mu;
    gmusig[2 * i]     = mu;
    gmusig[2 * i + 1] = rsqrtf(var + GNEPS);
  }
}

// ------------------------------------------------------------------
// K2: apply GN, cast bf16, TRANSPOSE -> xnT [b][n][c]
// grid (512 n-tiles of 64, 4 b), 256 thr
// ------------------------------------------------------------------
__global__ __launch_bounds__(256) void gn_apply(const float* __restrict__ x,
                                                const float* __restrict__ gamma,
                                                const float* __restrict__ beta,
                                                const float* __restrict__ gmusig,
                                                unsigned short* __restrict__ xnT) {
  __shared__ unsigned short s1[256 * 68];
  int b = blockIdx.y;
  int n0 = blockIdx.x * 64;
  const float* xb = x + (size_t)b * 256 * NTOK;
#pragma unroll
  for (int it = 0; it < 16; ++it) {
    int idx = threadIdx.x + it * 256;      // 4096 = 256c x 16 quads
    int c = idx >> 4, q = idx & 15;
    int g = c >> 6;
    float mu = gmusig[2 * (b * 4 + g)], rs = gmusig[2 * (b * 4 + g) + 1];
    float ga = gamma[c] * rs, be = beta[c] - mu * ga;
    f32x4 v = *reinterpret_cast<const f32x4*>(&xb[(size_t)c * NTOK + n0 + q * 4]);
    u16x4 o = { f2b(v.x * ga + be), f2b(v.y * ga + be),
                f2b(v.z * ga + be), f2b(v.w * ga + be) };
    *reinterpret_cast<u16x4*>(&s1[c * 68 + q * 4]) = o;
  }
  __syncthreads();
#pragma unroll
  for (int it = 0; it < 8; ++it) {
    int task = threadIdx.x + it * 256;     // 2048 = 64n x 32 octets
    int n = task >> 5, oc = task & 31;
    s16x8 pk;
#pragma unroll
    for (int i = 0; i < 8; ++i) pk[i] = (short)s1[(oc * 8 + i) * 68 + n];
    *reinterpret_cast<s16x8*>(&xnT[((size_t)(b * NTOK + n0 + n)) * 256 + oc * 8]) = pk;
  }
}

// ------------------------------------------------------------------
// K2b: w_qkv f32 -> bf16
// ------------------------------------------------------------------
__global__ __launch_bounds__(256) void cvt_w(const float* __restrict__ w,
                                             unsigned short* __restrict__ wb) {
  int i = blockIdx.x * 256 + threadIdx.x;
  f32x4 v = *reinterpret_cast<const f32x4*>(&w[(size_t)i * 4]);
  u16x4 o = { f2b(v.x), f2b(v.y), f2b(v.z), f2b(v.w) };
  *reinterpret_cast<u16x4*>(&wb[(size_t)i * 4]) = o;
}

// ------------------------------------------------------------------
// K3: qkv GEMM, m97 structure. 128x128 tile, BK=64, 256 thr (4 waves 2x2).
// A = wqkvb rows (global_load_lds), B = xnT rows (global_load_lds),
// both XOR-pre-swizzled at the source. q tiles (ot<2) written transposed
// to qT[n][o]; k/v tiles written to kvb[row][n]. LDS-bounce epilogues.
// ------------------------------------------------------------------
__global__ __launch_bounds__(256) void qkv_gemm(const unsigned short* __restrict__ wqkvb,
                                                const unsigned short* __restrict__ xnT,
                                                unsigned short* __restrict__ qT,
                                                unsigned short* __restrict__ kvb) {
  __shared__ unsigned short smem[16384];   // 32KB: A [0,8192) u16, B [8192,16384)
  unsigned short* As = smem;
  unsigned short* Bs = smem + 8192;
  int bid = blockIdx.x;
  int L = (bid & 7) * 768 + (bid >> 3);    // XCD swizzle, 6144 % 8 == 0
  int b = L / 1536; int rem = L % 1536; int ot = rem >> 8; int ntile = rem & 255;
  int n0 = ntile * 128;
  int tid = threadIdx.x;
  int w = tid >> 6, l = tid & 63;
  int wo = w >> 1, wn = w & 1;
  int lr = l >> 3, lj = l & 7;
  int srcj = lj ^ lr;                      // pre-swizzled source slot
  const unsigned short* Abase = wqkvb + (size_t)(ot * 128) * 256;
  const unsigned short* Bbase = xnT + ((size_t)(b * NTOK + n0)) * 256;

  f32x4 acc[4][4];
#pragma unroll
  for (int s = 0; s < 4; ++s)
#pragma unroll
    for (int n = 0; n < 4; ++n) acc[s][n] = (f32x4){0.f, 0.f, 0.f, 0.f};

  for (int c0 = 0; c0 < 256; c0 += 64) {
    __syncthreads();
#pragma unroll
    for (int q = 0; q < 4; ++q) {          // A: 16 chunks of 1024B over 4 waves
      int chunk = w * 4 + q; int row = chunk * 8 + lr;
      stage16(Abase + (size_t)row * 256 + c0 + srcj * 8, As + chunk * 512, l);
    }
#pragma unroll
    for (int q = 0; q < 4; ++q) {          // B: 16 chunks
      int chunk = w * 4 + q; int row = chunk * 8 + lr;
      stage16(Bbase + (size_t)row * 256 + c0 + srcj * 8, Bs + chunk * 512, l);
    }
    __syncthreads();
#pragma unroll
    for (int t = 0; t < 2; ++t) {
      s16x8 af[4], bf[4];
#pragma unroll
      for (int s = 0; s < 4; ++s) {
        int row = wo * 64 + s * 16 + (l & 15);
        int phys = (t * 4 + (l >> 4)) ^ (row & 7);
        af[s] = *reinterpret_cast<const s16x8*>(&As[row * 64 + phys * 8]);
      }
#pragma unroll
      for (int n = 0; n < 4; ++n) {
        int row = wn * 64 + n * 16 + (l & 15);
        int phys = (t * 4 + (l >> 4)) ^ (row & 7);
        bf[n] = *reinterpret_cast<const s16x8*>(&Bs[row * 64 + phys * 8]);
      }
#pragma unroll
      for (int s = 0; s < 4; ++s)
#pragma unroll
        for (int n = 0; n < 4; ++n)
          acc[s][n] = __builtin_amdgcn_mfma_f32_16x16x32_bf16(af[s], bf[n], acc[s][n], 0, 0, 0);
    }
  }

  // ---- epilogue: LDS bounce, 2 chunks of 64 o ----
  bool isQ = (ot < 2);
  for (int ch = 0; ch < 2; ++ch) {
    __syncthreads();
    if (wo == ch) {
#pragma unroll
      for (int s = 0; s < 4; ++s)
#pragma unroll
        for (int n = 0; n < 4; ++n)
#pragma unroll
          for (int i = 0; i < 4; ++i) {
            int o_l = s * 16 + (l >> 4) * 4 + i;           // 0..63
            int n_l = wn * 64 + n * 16 + (l & 15);         // 0..127
            unsigned short v = f2b(acc[s][n][i]);
            if (isQ) smem[n_l * 72 + o_l] = v;             // [128n][72]
            else     smem[o_l * 138 + n_l] = v;            // [64o][138]
          }
    }
    __syncthreads();
    if (isQ) {
#pragma unroll
      for (int it = 0; it < 4; ++it) {
        int task = tid + it * 256;                          // 1024 = 128n x 8
        int n_l = task >> 3, j = task & 7;
        s16x8 v = *reinterpret_cast<const s16x8*>(&smem[n_l * 72 + j * 8]);
        *reinterpret_cast<s16x8*>(&qT[((size_t)(b * NTOK + n0 + n_l)) * 256 + ot * 128 + ch * 64 + j * 8]) = v;
      }
    } else {
#pragma unroll
      for (int it = 0; it < 4; ++it) {
        int task = tid + it * 256;                          // 1024 = 64o x 16
        int o_l = task >> 4, j = task & 15;
        s16x8 v = *reinterpret_cast<const s16x8*>(&smem[o_l * 138 + j * 8]);
        int row = (ot - 2) * 128 + ch * 64 + o_l;           // kv row = o-256
        *reinterpret_cast<s16x8*>(&kvb[((size_t)(b * 512 + row)) * NTOK + n0 + j * 8]) = v;
      }
    }
  }
}

// ------------------------------------------------------------------
// K4: per-row max and 1/sum(exp) for k (kvb rows 0..255 per batch)
// ------------------------------------------------------------------
__global__ __launch_bounds__(256) void k_maxsum(const unsigned short* __restrict__ kvb,
                                                float* __restrict__ kmax,
                                                float* __restrict__ krsum) {
  int r = blockIdx.x;
  int b = r >> 8, hd = r & 255;
  const unsigned short* row = kvb + ((size_t)(b * 512) + hd) * NTOK;
  int tid = threadIdx.x;
  float m = -1e30f;
  for (int i = tid; i < 4096; i += 256) {
    s16x8 v = *reinterpret_cast<const s16x8*>(&row[i * 8]);
#pragma unroll
    for (int j = 0; j < 8; ++j) m = fmaxf(m, b2f((unsigned short)v[j]));
  }
  for (int o = 32; o > 0; o >>= 1) m = fmaxf(m, __shfl_down(m, o));
  __shared__ float sm[4], ss[4];
  int lane = tid & 63, w = tid >> 6;
  if (lane == 0) sm[w] = m;
  __syncthreads();
  float M = fmaxf(fmaxf(sm[0], sm[1]), fmaxf(sm[2], sm[3]));
  float s = 0.f;
  for (int i = tid; i < 4096; i += 256) {
    s16x8 v = *reinterpret_cast<const s16x8*>(&row[i * 8]);
#pragma unroll
    for (int j = 0; j < 8; ++j) s += __expf(b2f((unsigned short)v[j]) - M);
  }
  for (int o = 32; o > 0; o >>= 1) s += __shfl_down(s, o);
  if (lane == 0) ss[w] = s;
  __syncthreads();
  if (tid == 0) {
    kmax[r]  = M;
    krsum[r] = 1.f / (ss[0] + ss[1] + ss[2] + ss[3]);
  }
}

// ------------------------------------------------------------------
// K5: ctx[b][h][d][e] += sum_n softmax(k)[d][n] * v[e][n]
// ------------------------------------------------------------------
__global__ __launch_bounds__(256) void context_partial(const unsigned short* __restrict__ kvb,
                                                       const float* __restrict__ kmax,
                                                       const float* __restrict__ krsum,
                                                       float* __restrict__ ctx) {
  int bh = blockIdx.y;
  int b = bh >> 3, h = bh & 7;
  int n0 = blockIdx.x * 1024;
  const unsigned short* kb = kvb + ((size_t)(b * 512) + h * 32) * NTOK;
  const unsigned short* vb = kvb + ((size_t)(b * 512) + 256 + h * 32) * NTOK;
  __shared__ float kt[32][260];
  __shared__ float vt[32][260];
  int tid = threadIdx.x;
  int d2 = (tid >> 4) * 2;
  int e2 = (tid & 15) * 2;
  int rbase = b * 256 + h * 32;
  float acc[2][2] = {};
  for (int sub = 0; sub < 4; ++sub) {
    int nb = n0 + sub * 256;
    __syncthreads();
    for (int u = tid; u < 1024; u += 256) {
      int d = u >> 5, oc = u & 31;
      float km = kmax[rbase + d], kr = krsum[rbase + d];
      s16x8 kv = *reinterpret_cast<const s16x8*>(&kb[(size_t)d * NTOK + nb + oc * 8]);
      s16x8 vv = *reinterpret_cast<const s16x8*>(&vb[(size_t)d * NTOK + nb + oc * 8]);
#pragma unroll
      for (int j = 0; j < 8; ++j) {
        kt[d][oc * 8 + j] = __expf(b2f((unsigned short)kv[j]) - km) * kr;
        vt[d][oc * 8 + j] = b2f((unsigned short)vv[j]);
      }
    }
    __syncthreads();
#pragma unroll 8
    for (int t = 0; t < 256; ++t) {
      float k0 = kt[d2][t], k1 = kt[d2 + 1][t];
      float v0 = vt[e2][t], v1 = vt[e2 + 1][t];
      acc[0][0] += k0 * v0; acc[0][1] += k0 * v1;
      acc[1][0] += k1 * v0; acc[1][1] += k1 * v1;
    }
  }
  float* cb = ctx + (size_t)bh * 1024;
  atomicAdd(&cb[(d2)     * 32 + e2],     acc[0][0]);
  atomicAdd(&cb[(d2)     * 32 + e2 + 1], acc[0][1]);
  atomicAdd(&cb[(d2 + 1) * 32 + e2],     acc[1][0]);
  atomicAdd(&cb[(d2 + 1) * 32 + e2 + 1], acc[1][1]);
}

// ------------------------------------------------------------------
// K5b: wctx_b[b][o][h*32+d] = bf16( sum_e wout[o][h*32+e] * ctx[b][h][d][e] )
// ------------------------------------------------------------------
__global__ __launch_bounds__(256) void make_wctx(const float* __restrict__ wout,
                                                 const float* __restrict__ ctx,
                                                 unsigned short* __restrict__ wctxb) {
  int o = blockIdx.x, b = blockIdx.y;
  int tid = threadIdx.x;
  int h = tid >> 5, d = tid & 31;
  const float* cb = ctx + ((size_t)(b * 8 + h)) * 1024 + d * 32;
  const float* wr = wout + (size_t)o * 256 + h * 32;
  float s = 0.f;
#pragma unroll
  for (int e = 0; e < 32; ++e) s += wr[e] * cb[e];
  wctxb[((size_t)b * 256 + o) * 256 + tid] = f2b(s);
}

// ------------------------------------------------------------------
// K6: out = wctxb @ softmax_d(qT) + bias + x.  Same m97 GEMM structure;
// B staged from qT with fused per-(n,head) softmax (reg->swizzled ds_write).
// ------------------------------------------------------------------
__global__ __launch_bounds__(256) void out_gemm(const unsigned short* __restrict__ wctxb,
                                                const unsigned short* __restrict__ qT,
                                                const float* __restrict__ bout,
                                                const float* __restrict__ x,
                                                float* __restrict__ out) {
  __shared__ unsigned short As[8192];       // [128o][64] linear
  __shared__ unsigned short Bs[128 * 68];   // [128n][68] padded, swizzled
  int bid = blockIdx.x;
  int L = (bid & 7) * 256 + (bid >> 3);     // 2048 % 8 == 0
  int b = L / 512; int rem = L % 512; int ot = rem >> 8; int ntile = rem & 255;
  int n0 = ntile * 128;
  int tid = threadIdx.x;
  int w = tid >> 6, l = tid & 63;
  int wo = w >> 1, wn = w & 1;
  int lr = l >> 3, lj = l & 7;
  int srcj = lj ^ lr;
  const unsigned short* Abase = wctxb + ((size_t)(b * 256 + ot * 128)) * 256;
  const unsigned short* qbase = qT + ((size_t)(b * NTOK + n0)) * 256;

  f32x4 acc[4][4];
#pragma unroll
  for (int s = 0; s < 4; ++s)
#pragma unroll
    for (int n = 0; n < 4; ++n) acc[s][n] = (f32x4){0.f, 0.f, 0.f, 0.f};

  for (int c0 = 0; c0 < 256; c0 += 64) {
    __syncthreads();
#pragma unroll
    for (int q = 0; q < 4; ++q) {
      int chunk = w * 4 + q; int row = chunk * 8 + lr;
      stage16(Abase + (size_t)row * 256 + c0 + srcj * 8, As + chunk * 512, l);
    }
    // B: fused q-softmax staging. task = tid: n = tid>>1, head-half = tid&1
    {
      int n = tid >> 1, hl = tid & 1;
      const unsigned short* qr = qbase + (size_t)n * 256 + c0 + hl * 32;
      float v[32];
#pragma unroll
      for (int q2 = 0; q2 < 4; ++q2) {
        s16x8 r = *reinterpret_cast<const s16x8*>(&qr[q2 * 8]);
#pragma unroll
        for (int i = 0; i < 8; ++i) v[q2 * 8 + i] = b2f((unsigned short)r[i]);
      }
      float m = v[0];
#pragma unroll
      for (int i = 1; i < 32; ++i) m = fmaxf(m, v[i]);
      float ssum = 0.f;
#pragma unroll
      for (int i = 0; i < 32; ++i) { v[i] = __expf(v[i] - m); ssum += v[i]; }
      float rr = 1.f / ssum;
#pragma unroll
      for (int q2 = 0; q2 < 4; ++q2) {
        s16x8 pk;
#pragma unroll
        for (int i = 0; i < 8; ++i) pk[i] = (short)f2b(v[q2 * 8 + i] * rr);
        int phys = (hl * 4 + q2) ^ (n & 7);
        *reinterpret_cast<s16x8*>(&Bs[n * 68 + phys * 8]) = pk;
      }
    }
    __syncthreads();
#pragma unroll
    for (int t = 0; t < 2; ++t) {
      s16x8 af[4], bf[4];
#pragma unroll
      for (int s = 0; s < 4; ++s) {
        int row = wo * 64 + s * 16 + (l & 15);
        int phys = (t * 4 + (l >> 4)) ^ (row & 7);
        af[s] = *reinterpret_cast<const s16x8*>(&As[row * 64 + phys * 8]);
      }
#pragma unroll
      for (int n = 0; n < 4; ++n) {
        int row = wn * 64 + n * 16 + (l & 15);
        int phys = (t * 4 + (l >> 4)) ^ (row & 7);
        bf[n] = *reinterpret_cast<const s16x8*>(&Bs[row * 68 + phys * 8]);
      }
#pragma unroll
      for (int s = 0; s < 4; ++s)
#pragma unroll
        for (int n = 0; n < 4; ++n)
          acc[s][n] = __builtin_amdgcn_mfma_f32_16x16x32_bf16(af[s], bf[n], acc[s][n], 0, 0, 0);
    }
  }

  const float* xb = x + (size_t)b * 256 * NTOK;
#pragma unroll
  for (int s = 0; s < 4; ++s)
#pragma unroll
    for (int i = 0; i < 4; ++i) {
      int o = ot * 128 + wo * 64 + s * 16 + (l >> 4) * 4 + i;
      float bo = bout[o];
#pragma unroll
      for (int n = 0; n < 4; ++n) {
        int nn = n0 + wn * 64 + n * 16 + (l & 15);
        out[((size_t)b * 256 + o) * NTOK + nn] = acc[s][n][i] + bo + xb[(size_t)o * NTOK + nn];
      }
    }
}

// ------------------------------------------------------------------
extern "C" void kernel_launch(void* const* d_in, const int* in_sizes, int n_in,
                              void* d_out, int out_size, void* d_ws, size_t ws_size,
                              hipStream_t stream) {
  const float* x     = (const float*)d_in[0];
  const float* gamma = (const float*)d_in[1];
  const float* beta  = (const float*)d_in[2];
  const float* wqkv  = (const float*)d_in[3];
  const float* wout  = (const float*)d_in[4];
  const float* bout  = (const float*)d_in[5];
  float* out = (float*)d_out;

  if (ws_size < WS_NEEDED) return;

  char* ws = (char*)d_ws;
  float* gstat  = (float*)(ws + OFF_GSTAT);
  float* gmusig = (float*)(ws + OFF_GMUSIG);
  float* kmax   = (float*)(ws + OFF_KMAX);
  float* krsum  = (float*)(ws + OFF_KRSUM);
  float* ctx    = (float*)(ws + OFF_CTX);
  unsigned short* wctxb = (unsigned short*)(ws + OFF_WCTXB);
  unsigned short* wqkvb = (unsigned short*)(ws + OFF_WQKVB);
  unsigned short* xnT   = (unsigned short*)(ws + OFF_XNT);
  unsigned short* qT    = (unsigned short*)(ws + OFF_QT);
  unsigned short* kvb   = (unsigned short*)(ws + OFF_KVB);

  hipMemsetAsync(ws, 0, OFF_CTX + 131072u, stream);

  gn_partial  <<<dim3(64, 16), 256, 0, stream>>>(x, gstat);
  gn_finalize <<<1, 64, 0, stream>>>(gstat, gmusig);
  cvt_w       <<<192, 256, 0, stream>>>(wqkv, wqkvb);
  gn_apply    <<<dim3(512, 4), 256, 0, stream>>>(x, gamma, beta, gmusig, xnT);
  qkv_gemm    <<<6144, 256, 0, stream>>>(wqkvb, xnT, qT, kvb);
  k_maxsum    <<<1024, 256, 0, stream>>>(kvb, kmax, krsum);
  context_partial<<<dim3(32, 32), 256, 0, stream>>>(kvb, kmax, krsum, ctx);
  make_wctx   <<<dim3(256, 4), 256, 0, stream>>>(wout, ctx, wctxb);
  out_gemm    <<<2048, 256, 0, stream>>>(wctxb, qT, bout, x, out);
}